// Round 7
// baseline (139.300 us; speedup 1.0000x reference)
//
#include <hip/hip_runtime.h>

#define BATCH 16
#define HH 512
#define WW 512
#define RSLICE 8
#define NSLICE (HH / RSLICE)   // 64

static constexpr size_t PLANE = (size_t)HH * WW;
static constexpr size_t COLP_ELEMS = (size_t)BATCH * NSLICE * WW; // 524288 floats (2 MB)
static constexpr size_t ROWS_ELEMS = (size_t)BATCH * HH;          // 8192 floats

// clang-native vector types: __builtin_nontemporal_load/store accepts these
// (it rejects HIP_vector_type float4/float2 -- round 6 compile failure).
typedef float fx4 __attribute__((ext_vector_type(4)));
typedef float fx2 __attribute__((ext_vector_type(2)));

__device__ __forceinline__ float lum3(float a, float b, float c) {
  return 0.299f * a + 0.587f * b + 0.114f * c;
}

// Kernel A, LDS-luminance design + NON-TEMPORAL input reads.
// Rounds 3/4/5: three different structures all capped at ~33 us (~3.4 TB/s)
// -> structure-independent: the harness's in-graph 268 MB ws-poison fill
// leaves L3 full of dirty lines; our streaming reads then pay one dirty
// writeback per L3 allocation (~2x traffic). nt loads (no L3 allocate)
// sidestep the eviction storm. Halo rows re-fetch from HBM (+12.5%), fine.
__global__ __launch_bounds__(256) void jbd_reduce(const float* __restrict__ ref,
                                                  const float* __restrict__ tgt,
                                                  float* __restrict__ colp,
                                                  float* __restrict__ rows) {
  const int t = threadIdx.x;          // 0..255
  const int lane = t & 63;
  const int wid = t >> 6;
  const int slice = blockIdx.x & (NSLICE - 1);
  const int b = blockIdx.x >> 6;      // / NSLICE
  const int r0 = slice * RSLICE;
  __shared__ float Lr[RSLICE + 1][WW];   // ref luminance rows r0..r0+8
  __shared__ float Lt[RSLICE + 1][WW];   // tgt luminance
  __shared__ float rowpart[RSLICE][4];

  // ---- Pass 1: luminance -> LDS (27 independent nt 16B loads) ----
  {
    const int g = t >> 7;             // 0 = ref, 1 = tgt
    const int u = t & 127;            // cols 4u..4u+3
    const float* base = (g ? tgt : ref) + (size_t)b * 3 * PLANE;
    float* L = g ? &Lt[0][0] : &Lr[0][0];
#pragma unroll
    for (int k = 0; k <= RSLICE; ++k) {
      const int row = min(r0 + k, HH - 1);   // slice 63 dup of row 511: unread
      const size_t o = (size_t)row * WW + 4 * u;
      const fx4 p0 = __builtin_nontemporal_load((const fx4*)(base + o));
      const fx4 p1 = __builtin_nontemporal_load((const fx4*)(base + o + PLANE));
      const fx4 p2 = __builtin_nontemporal_load((const fx4*)(base + o + 2 * PLANE));
      fx4 l;
      l.x = lum3(p0.x, p1.x, p2.x);
      l.y = lum3(p0.y, p1.y, p2.y);
      l.z = lum3(p0.z, p1.z, p2.z);
      l.w = lum3(p0.w, p1.w, p2.w);
      *(fx4*)&L[k * WW + 4 * u] = l;
    }
  }
  __syncthreads();

  // ---- Pass 2: diffs + reductions. Thread t owns cols 2t, 2t+1. ----
  float ca0 = 0.f, ca1 = 0.f;
  const int c0i = 2 * t;
  float lr0 = Lr[0][c0i], lr1 = Lr[0][c0i + 1];
  float lt0 = Lt[0][c0i], lt1 = Lt[0][c0i + 1];
#pragma unroll
  for (int i = 0; i < RSLICE; ++i) {
    // de_h for row r0+i (neighbor col 2t+2; t==255 has no col 512 -> guarded;
    // the read itself stays in-bounds: Lr[i][512] aliases Lr[i+1][0])
    const float nlr = Lr[i][c0i + 2];
    const float nlt = Lt[i][c0i + 2];
    ca0 += fmaxf(fabsf(lt0 - lt1) - fabsf(lr0 - lr1), 0.f);
    if (t < 255)
      ca1 += fmaxf(fabsf(lt1 - nlt) - fabsf(lr1 - nlr), 0.f);
    // de_v row h = r0+i uses lum rows h, h+1
    const float xr0 = Lr[i + 1][c0i], xr1 = Lr[i + 1][c0i + 1];
    const float xt0 = Lt[i + 1][c0i], xt1 = Lt[i + 1][c0i + 1];
    float dv = 0.f;
    if (r0 + i < HH - 1) {               // block-uniform guard (h<=510 valid)
      dv = fmaxf(fabsf(xt0 - lt0) - fabsf(xr0 - lr0), 0.f)
         + fmaxf(fabsf(xt1 - lt1) - fabsf(xr1 - lr1), 0.f);
    }
    dv += __shfl_xor(dv, 1);
    dv += __shfl_xor(dv, 2);
    dv += __shfl_xor(dv, 4);
    dv += __shfl_xor(dv, 8);
    dv += __shfl_xor(dv, 16);
    dv += __shfl_xor(dv, 32);
    if (lane == 0) rowpart[i][wid] = dv;
    lr0 = xr0; lr1 = xr1; lt0 = xt0; lt1 = xt1;
  }
  __syncthreads();
  if (t < RSLICE) {
    const int h = r0 + t;
    if (h < HH - 1)                      // de_v rows are 0..510
      __builtin_nontemporal_store(
          rowpart[t][0] + rowpart[t][1] + rowpart[t][2] + rowpart[t][3],
          &rows[(size_t)b * HH + h]);
  }
  fx2 cw;
  cw.x = ca0; cw.y = ca1;
  __builtin_nontemporal_store(
      cw, (fx2*)&colp[((size_t)b * NSLICE + slice) * WW + c0i]);
}

// Kernel B: block per (direction, batch), 64 threads. Thread t owns the 8
// consecutive lines 8t..8t+7 (phase = j directly). float4 loads, per-phase
// butterfly reduce, then uniform 8-way argmax (strict > = first-index ties).
__global__ __launch_bounds__(64) void jbd_phase(const float* __restrict__ colp,
                                                const float* __restrict__ rows,
                                                int* __restrict__ results) {
  const int dir = blockIdx.x & 1;   // 0 = columns (de_h), 1 = rows (de_v)
  const int b = blockIdx.x >> 1;
  const int t = threadIdx.x;        // 0..63
  float c0 = 0.f, c1 = 0.f, c2 = 0.f, c3 = 0.f;
  float c4 = 0.f, c5 = 0.f, c6 = 0.f, c7 = 0.f;
  if (dir == 0) {
#pragma unroll 4
    for (int sl = 0; sl < NSLICE; ++sl) {
      const float* p = colp + ((size_t)b * NSLICE + sl) * WW + 8 * t;
      const float4 u = *(const float4*)p;
      const float4 v = *(const float4*)(p + 4);
      c0 += u.x; c1 += u.y; c2 += u.z; c3 += u.w;
      c4 += v.x; c5 += v.y; c6 += v.z; c7 += v.w;
    }
  } else {
    const float* p = rows + (size_t)b * HH + 8 * t;
    const float4 u = *(const float4*)p;
    const float4 v = *(const float4*)(p + 4);
    c0 = u.x; c1 = u.y; c2 = u.z; c3 = u.w;
    c4 = v.x; c5 = v.y; c6 = v.z; c7 = v.w;
  }
  if (t == 63) c7 = 0.f;            // line 511 does not exist (511 lines)
  float ps[8] = {c0, c1, c2, c3, c4, c5, c6, c7};
  float tot = 0.f;
#pragma unroll
  for (int p = 0; p < 8; ++p) {
    float v = ps[p];
    v += __shfl_xor(v, 1);
    v += __shfl_xor(v, 2);
    v += __shfl_xor(v, 4);
    v += __shfl_xor(v, 8);
    v += __shfl_xor(v, 16);
    v += __shfl_xor(v, 32);
    v *= (1.0f / 512.0f);           // line-mean divisor (H resp. W = 512)
    ps[p] = v;
    tot += v;
  }
  float best = -1.f;
  int bk = 0;
#pragma unroll
  for (int p = 0; p < 8; ++p) {
    const float cnt = (p == 7) ? 63.f : 64.f;  // phases 0..6 -> 64 lines, 7 -> 63
    const float a_k = ps[p] / cnt;
    const float bg = (tot - ps[p]) / (511.f - cnt);
    const float r = a_k / (bg + 1e-8f);
    if (r > best) { best = r; bk = p; }
  }
  if (t == 0) {
    results[4 * b + 2 * dir] = bk;
    results[4 * b + 2 * dir + 1] = (best > (float)(1.0 / 0.35)) ? 1 : 0;
  }
}

// Kernel C: broadcast per-batch decisions to the (B,1,H,W) mask; nt 16B
// stores (no L3 allocate -- the mask is only re-read by untimed validation).
__global__ __launch_bounds__(256) void jbd_write(const int* __restrict__ results,
                                                 float* __restrict__ out) {
  const int idx = blockIdx.x * 256 + threadIdx.x;  // fx4 index
  const int b = idx >> 16;          // 512*128 fx4 per batch
  const int rem = idx & 65535;
  const int h = rem >> 7;
  const int wq = rem & 127;
  const int4 rs = ((const int4*)results)[b];  // {bk_h, blocked_h, bk_v, blocked_v}
  const bool rowm = (rs.w != 0) && ((h & 7) == rs.z) && (h < HH - 1);
  fx4 o;
  const int w0 = wq << 2;
#pragma unroll
  for (int j = 0; j < 4; ++j) {
    const int w = w0 + j;
    const bool colm = (rs.y != 0) && ((w & 7) == rs.x) && (w < WW - 1);
    o[j] = (rowm || colm) ? 1.0f : 0.0f;
  }
  __builtin_nontemporal_store(o, (fx4*)out + idx);
}

extern "C" void kernel_launch(void* const* d_in, const int* in_sizes, int n_in,
                              void* d_out, int out_size, void* d_ws, size_t ws_size,
                              hipStream_t stream) {
  (void)in_sizes; (void)n_in; (void)out_size; (void)ws_size;
  const float* ref = (const float*)d_in[0];
  const float* tgt = (const float*)d_in[1];
  float* colp = (float*)d_ws;                 // [B][NSLICE][W]
  float* rows = colp + COLP_ELEMS;            // [B][H] (index 511 unused)
  int* results = (int*)(rows + ROWS_ELEMS);   // [B][4]
  jbd_reduce<<<BATCH * NSLICE, 256, 0, stream>>>(ref, tgt, colp, rows);
  jbd_phase<<<2 * BATCH, 64, 0, stream>>>(colp, rows, results);
  jbd_write<<<(BATCH * HH * WW / 4) / 256, 256, 0, stream>>>(results, (float*)d_out);
}